// Round 12
// baseline (307.326 us; speedup 1.0000x reference)
//
#include <hip/hip_runtime.h>

// ---------------- problem constants ----------------
#define H_DIM 256
#define E_NUM 524288
#define NN    32768          // B*N nodes
#define K2    512            // 2H
#define K2S   520            // LDS row stride (u16) k_post A-tile
#define SAS   264            // LDS row stride (u16) for 256-wide A tiles
#define XS    264            // fp32 intermediate row stride in k_post

typedef unsigned short u16;
typedef unsigned int   u32;
typedef __attribute__((ext_vector_type(8))) short s16x8;
typedef __attribute__((ext_vector_type(4))) float f32x4;
typedef __attribute__((ext_vector_type(2))) float f32x2;
typedef __attribute__((ext_vector_type(4))) unsigned short u16x4;

__device__ __forceinline__ u16 f2b(float x) {
    u32 u = __float_as_uint(x);
    u32 r = (u + 0x7FFFu + ((u >> 16) & 1u)) >> 16;   // RNE; inputs finite
    return (u16)r;
}
__device__ __forceinline__ float b2f(u16 v) {
    u32 u = ((u32)v) << 16;
    return __uint_as_float(u);
}
__device__ __forceinline__ float fsig(float x) {       // fast sigmoid
    return __builtin_amdgcn_rcpf(1.f + __expf(-x));
}

// ---------------- weight prep: build bf16 transposed weights ----------------
__global__ __launch_bounds__(256) void k_prep_w(
    const float* __restrict__ W1, const float* __restrict__ W2,
    const float* __restrict__ U1, const float* __restrict__ U2,
    u16* __restrict__ WpqT, u16* __restrict__ W2T,
    u16* __restrict__ U1T, u16* __restrict__ U2T) {
    int idx = blockIdx.x * 256 + threadIdx.x;
    if (idx < 131072) {                       // WpqT
        int c = idx >> 8, k = idx & 255;
        float v = (c < 256) ? W1[k * 256 + c] : W1[(256 + k) * 256 + (c - 256)];
        WpqT[idx] = f2b(v);
    } else if (idx < 196608) {                // W2T
        int i = idx - 131072; int c = i >> 8, k = i & 255;
        W2T[i] = f2b(W2[k * 256 + c]);
    } else if (idx < 327680) {                // U1T
        int i = idx - 196608; int c = i >> 9, k = i & 511;
        U1T[i] = f2b(U1[(size_t)k * 256 + c]);
    } else if (idx < 393216) {                // U2T
        int i = idx - 327680; int c = i >> 8, k = i & 255;
        U2T[i] = f2b(U2[k * 256 + c]);
    }
}

// ---------------- CSR build ----------------
__global__ __launch_bounds__(256) void k_hist(const int* __restrict__ eidx,
                                              int* __restrict__ cnt) {
    int i = blockIdx.x * 256 + threadIdx.x;
    if (i < E_NUM) atomicAdd(&cnt[eidx[E_NUM + i]], 1);
}

// parallel scan: per-thread 128-chunk sums, wave shfl-scan, LDS cross-wave combine
__global__ __launch_bounds__(256) void k_scan(const int* __restrict__ cnt,
                                              int* __restrict__ base,
                                              int* __restrict__ nxt) {
    __shared__ int wsum[4];
    const int t = threadIdx.x, lane = t & 63, w = t >> 6;
    const int st = t * 128;
    int s = 0;
#pragma unroll 8
    for (int i = 0; i < 128; ++i) s += cnt[st + i];
    int sc = s;                               // inclusive scan within wave
#pragma unroll
    for (int off = 1; off < 64; off <<= 1) {
        int v = __shfl_up(sc, off);
        if (lane >= off) sc += v;
    }
    if (lane == 63) wsum[w] = sc;
    __syncthreads();
    int woff = 0;
    for (int i = 0; i < w; ++i) woff += wsum[i];
    const int excl = woff + sc - s;           // exclusive prefix of this thread's chunk
    if (t == 255) base[NN] = woff + sc;
    int off = excl;
    for (int i = 0; i < 128; ++i) {
        int v = cnt[st + i];
        base[st + i] = off;
        nxt[st + i] = off;
        off += v;
    }
}

// scatter: CSR src list + permutation index (small scattered writes only)
__global__ __launch_bounds__(256) void k_scatter(const int* __restrict__ eidx,
                                                 int* __restrict__ nxt,
                                                 int* __restrict__ elist,
                                                 int* __restrict__ eperm) {
    int i = blockIdx.x * 256 + threadIdx.x;
    if (i < E_NUM) {
        int d = eidx[E_NUM + i];
        int p = atomicAdd(&nxt[d], 1);
        elist[p] = eidx[i];
        eperm[p] = i;
    }
}

// permute ea rows into CSR order: random 64B reads (L3), coalesced writes
__global__ __launch_bounds__(256) void k_permute(const int* __restrict__ eperm,
                                                 const float* __restrict__ ea,
                                                 float* __restrict__ eas) {
    int p = blockIdx.x * 256 + threadIdx.x;
    if (p < E_NUM) {
        int i = eperm[p];
        const float4* s = reinterpret_cast<const float4*>(ea + (size_t)i * 16);
        float4 v0 = s[0], v1 = s[1], v2 = s[2], v3 = s[3];
        float4* o = reinterpret_cast<float4*>(eas + (size_t)p * 16);
        o[0] = v0; o[1] = v1; o[2] = v2; o[3] = v3;
    }
}

// ---------------- node GEMM: [P|Q] = h @ [W1a|W1b]  (bf16 out, NN x 512) ----------------
__global__ __launch_bounds__(256, 2) void k_gemm_pq(
    const float* __restrict__ h, const u16* __restrict__ WpqT,
    u16* __restrict__ PQ) {
    __shared__ __align__(16) u16 sA[64 * SAS];
    const int t = threadIdx.x;
    const int rowTile = blockIdx.x >> 1, q = blockIdx.x & 1;
    const int n0 = rowTile * 64;
    {   // stage h tile (fp32 -> bf16)
        const int r = t >> 2, g = t & 3;
        const float* hrow = h + (size_t)(n0 + r) * 256;
        u16* rowp = sA + r * SAS;
#pragma unroll
        for (int j = 0; j < 8; ++j) {
            const int c = g + 4 * j;
            float4 v0 = *reinterpret_cast<const float4*>(hrow + c * 8);
            float4 v1 = *reinterpret_cast<const float4*>(hrow + c * 8 + 4);
            s16x8 o;
            o[0] = (short)f2b(v0.x); o[1] = (short)f2b(v0.y);
            o[2] = (short)f2b(v0.z); o[3] = (short)f2b(v0.w);
            o[4] = (short)f2b(v1.x); o[5] = (short)f2b(v1.y);
            o[6] = (short)f2b(v1.z); o[7] = (short)f2b(v1.w);
            *reinterpret_cast<s16x8*>(rowp + c * 8) = o;
        }
    }
    __syncthreads();
    const int lane = t & 63, wv = t >> 6;
    const int l15 = lane & 15, l4 = lane >> 4;
    const int colBase = wv * 64 + l15;
    const f32x4 z4 = {0.f, 0.f, 0.f, 0.f};
    f32x4 acc[4][4];
#pragma unroll
    for (int m = 0; m < 4; ++m)
#pragma unroll
        for (int n = 0; n < 4; ++n) acc[m][n] = z4;
    {
        const u16* Bb = WpqT + (size_t)(q * 256 + colBase) * 256 + l4 * 8;
        for (int kk = 0; kk < 8; ++kk) {
            s16x8 a[4], b[4];
#pragma unroll
            for (int m = 0; m < 4; ++m)
                a[m] = *reinterpret_cast<const s16x8*>(sA + (m * 16 + l15) * SAS + kk * 32 + l4 * 8);
#pragma unroll
            for (int n = 0; n < 4; ++n)
                b[n] = *reinterpret_cast<const s16x8*>(Bb + (size_t)n * 16 * 256 + kk * 32);
#pragma unroll
            for (int m = 0; m < 4; ++m)
#pragma unroll
                for (int n = 0; n < 4; ++n)
                    acc[m][n] = __builtin_amdgcn_mfma_f32_16x16x32_bf16(a[m], b[n], acc[m][n], 0, 0, 0);
        }
    }
#pragma unroll
    for (int m = 0; m < 4; ++m)
#pragma unroll
        for (int j = 0; j < 4; ++j) {
            const int row = n0 + m * 16 + l4 * 4 + j;
            u16* op = PQ + (size_t)row * 512 + q * 256 + colBase;
#pragma unroll
            for (int n = 0; n < 4; ++n) op[n * 16] = f2b(acc[m][n][j]);
        }
}

// ---------------- aggregation: S[d] = sum_e silu(P[src]+Q[d]+R[e]), bf16 out ----------------
// grid = NN/4 blocks x 4 waves; ONE dst node per wave (4x wave oversubscription for TLP).
// depth-4 pipelined PQ gathers; ea pre-sorted to CSR order -> sequential uniform loads.
// (R9 configuration: proven best at ~103 us; pins/attrs regressed in R10/R11.)

// load CSR-ordered ea row (uniform, sequential) for window edge k (clamped to m-1)
#define LDEA(S0, S1, S2, S3, k) do {                                        \
    const float* _ep = eas + (size_t)(eBeg + cb + min((k), m - 1)) * 16;    \
    S0 = *reinterpret_cast<const float4*>(_ep);                             \
    S1 = *reinterpret_cast<const float4*>(_ep + 4);                         \
    S2 = *reinterpret_cast<const float4*>(_ep + 8);                         \
    S3 = *reinterpret_cast<const float4*>(_ep + 12);                        \
} while (0)

__global__ __launch_bounds__(256, 4) void k_aggr(
    const u16* __restrict__ PQ, const int* __restrict__ elist,
    const int* __restrict__ base, const float* __restrict__ eas,
    const float* __restrict__ W1, const float* __restrict__ b1,
    u16* __restrict__ Sb) {
    const int t = threadIdx.x, lane = t & 63, wv = t >> 6;
    const int c0 = lane * 4;
    // W1c (rows 512..527) in registers as f32x2 pairs (v_pk_fma_f32)
    f32x2 WrL[16], WrH[16];
#pragma unroll
    for (int k = 0; k < 16; ++k) {
        float4 w = *reinterpret_cast<const float4*>(W1 + (size_t)(512 + k) * 256 + c0);
        WrL[k] = f32x2{w.x, w.y};
        WrH[k] = f32x2{w.z, w.w};
    }
    const float4 b1v = *reinterpret_cast<const float4*>(b1 + c0);

    const int d = __builtin_amdgcn_readfirstlane(blockIdx.x * 4 + wv);
    f32x2 qbL = {b1v.x, b1v.y}, qbH = {b1v.z, b1v.w};
    {
        u16x4 qv = *reinterpret_cast<const u16x4*>(PQ + (size_t)d * 512 + 256 + c0);
        qbL[0] += b2f(qv.x); qbL[1] += b2f(qv.y);
        qbH[0] += b2f(qv.z); qbH[1] += b2f(qv.w);
    }
    const int eBeg = __builtin_amdgcn_readfirstlane(base[d]);
    const int nAll = __builtin_amdgcn_readfirstlane(base[d + 1]) - eBeg;
    f32x2 accL = {0.f, 0.f}, accH = {0.f, 0.f};

    for (int cb = 0; cb < nAll; cb += 64) {
        const int m = min(64, nAll - cb);
        // lane-own src staging (lanes >= m duplicate edge m-1) -> any readlane idx<64 safe
        const int eeX = elist[eBeg + cb + min(lane, m - 1)];

        auto gather = [&](int idx) -> u16x4 {
            const int s = __builtin_amdgcn_readlane(eeX, idx);   // SGPR base
            return *reinterpret_cast<const u16x4*>(PQ + (size_t)s * 512 + c0);
        };
        auto edge_compute = [&](const u16x4& pc, const float4& E0, const float4& E1,
                                const float4& E2, const float4& E3) {
            f32x2 xL = qbL, xH = qbH;
            xL[0] += b2f(pc.x); xL[1] += b2f(pc.y);
            xH[0] += b2f(pc.z); xH[1] += b2f(pc.w);
            xL = xL + WrL[0]  * E0.x; xH = xH + WrH[0]  * E0.x;
            xL = xL + WrL[1]  * E0.y; xH = xH + WrH[1]  * E0.y;
            xL = xL + WrL[2]  * E0.z; xH = xH + WrH[2]  * E0.z;
            xL = xL + WrL[3]  * E0.w; xH = xH + WrH[3]  * E0.w;
            xL = xL + WrL[4]  * E1.x; xH = xH + WrH[4]  * E1.x;
            xL = xL + WrL[5]  * E1.y; xH = xH + WrH[5]  * E1.y;
            xL = xL + WrL[6]  * E1.z; xH = xH + WrH[6]  * E1.z;
            xL = xL + WrL[7]  * E1.w; xH = xH + WrH[7]  * E1.w;
            xL = xL + WrL[8]  * E2.x; xH = xH + WrH[8]  * E2.x;
            xL = xL + WrL[9]  * E2.y; xH = xH + WrH[9]  * E2.y;
            xL = xL + WrL[10] * E2.z; xH = xH + WrH[10] * E2.z;
            xL = xL + WrL[11] * E2.w; xH = xH + WrH[11] * E2.w;
            xL = xL + WrL[12] * E3.x; xH = xH + WrH[12] * E3.x;
            xL = xL + WrL[13] * E3.y; xH = xH + WrH[13] * E3.y;
            xL = xL + WrL[14] * E3.z; xH = xH + WrH[14] * E3.z;
            xL = xL + WrL[15] * E3.w; xH = xH + WrH[15] * E3.w;
            accL[0] += xL[0] * fsig(xL[0]);
            accL[1] += xL[1] * fsig(xL[1]);
            accH[0] += xH[0] * fsig(xH[0]);
            accH[1] += xH[1] * fsig(xH[1]);
        };

        // pipeline: depth-4 p-gathers, depth-2 ea buffers (A/B), all named regs
        u16x4 p0 = gather(0), p1 = gather(1), p2 = gather(2), p3 = gather(3);
        float4 A0, A1, A2, A3, B0, B1, B2, B3;
        LDEA(A0, A1, A2, A3, 0);
        LDEA(B0, B1, B2, B3, 1);
        int kb = 0;
        for (; kb + 4 <= m; kb += 4) {
            edge_compute(p0, A0, A1, A2, A3);
            LDEA(A0, A1, A2, A3, kb + 2);
            p0 = gather(min(kb + 4, 63));
            edge_compute(p1, B0, B1, B2, B3);
            LDEA(B0, B1, B2, B3, kb + 3);
            p1 = gather(min(kb + 5, 63));
            edge_compute(p2, A0, A1, A2, A3);
            LDEA(A0, A1, A2, A3, kb + 4);
            p2 = gather(min(kb + 6, 63));
            edge_compute(p3, B0, B1, B2, B3);
            LDEA(B0, B1, B2, B3, kb + 5);
            p3 = gather(min(kb + 7, 63));
        }
        // tail (<=3 edges); after loop A holds ea[kb], B holds ea[kb+1] (clamped)
        if (kb + 0 < m) edge_compute(p0, A0, A1, A2, A3);
        if (kb + 1 < m) edge_compute(p1, B0, B1, B2, B3);
        if (kb + 2 < m) {
            LDEA(A0, A1, A2, A3, kb + 2);
            edge_compute(p2, A0, A1, A2, A3);
        }
    }
    u16x4 o;
    o.x = f2b(accL[0]); o.y = f2b(accL[1]);
    o.z = f2b(accH[0]); o.w = f2b(accH[1]);
    *reinterpret_cast<u16x4*>(Sb + (size_t)d * 256 + c0) = o;
}

// ---------------- fused: aggr GEMM (Sb@W2 + deg*b2) + update MLP + residual + LN + mask ----------------
__global__ __launch_bounds__(256, 2) void k_post(
    const float* __restrict__ h, const u16* __restrict__ Sb,
    const u16* __restrict__ W2T, const int* __restrict__ base,
    const float* __restrict__ b2,
    const u16* __restrict__ U1T, const u16* __restrict__ U2T,
    const float* __restrict__ c1, const float* __restrict__ c2,
    const float* __restrict__ gamma, const float* __restrict__ beta,
    const float* __restrict__ mask,
    float* __restrict__ out) {
    __shared__ __align__(16) char smemraw[64 * XS * 4];  // 67584 B, multi-purpose
    u16* sA = reinterpret_cast<u16*>(smemraw);           // [64][K2S] bf16
    const int t  = threadIdx.x;
    const int n0 = blockIdx.x * 64;

    {   // stage [h(bf16) | Sb] -> sA
        const int r = t >> 2, g = t & 3;
        const int node = n0 + r;
        const float* hrow = h + (size_t)node * H_DIM;
        const u16* srow = Sb + (size_t)node * H_DIM;
        u16* rowp = sA + r * K2S;
#pragma unroll
        for (int j = 0; j < 16; ++j) {
            const int c = g + 4 * j;   // 0..63
            if (c < 32) {
                float4 v0 = *reinterpret_cast<const float4*>(hrow + c * 8);
                float4 v1 = *reinterpret_cast<const float4*>(hrow + c * 8 + 4);
                s16x8 o;
                o[0] = (short)f2b(v0.x); o[1] = (short)f2b(v0.y);
                o[2] = (short)f2b(v0.z); o[3] = (short)f2b(v0.w);
                o[4] = (short)f2b(v1.x); o[5] = (short)f2b(v1.y);
                o[6] = (short)f2b(v1.z); o[7] = (short)f2b(v1.w);
                *reinterpret_cast<s16x8*>(rowp + c * 8) = o;
            } else {
                const int cc = c - 32;
                *reinterpret_cast<s16x8*>(rowp + 256 + cc * 8) =
                    *reinterpret_cast<const s16x8*>(srow + cc * 8);
            }
        }
    }
    __syncthreads();

    const int lane = t & 63, wv = t >> 6;
    const int l15 = lane & 15, l4 = lane >> 4;
    const int colBase = wv * 64 + l15;
    const f32x4 z4 = {0.f, 0.f, 0.f, 0.f};

    f32x4 acc[4][4];
#pragma unroll
    for (int m = 0; m < 4; ++m)
#pragma unroll
        for (int n = 0; n < 4; ++n) acc[m][n] = z4;

    // ---- GEMM-S: aggr = Sb @ W2 (A from sA[256..511], K=256) ----
    {
        const u16* Bb = W2T + (size_t)colBase * 256 + l4 * 8;
        for (int kk = 0; kk < 8; ++kk) {
            s16x8 a[4], b[4];
#pragma unroll
            for (int m = 0; m < 4; ++m)
                a[m] = *reinterpret_cast<const s16x8*>(sA + (m * 16 + l15) * K2S + 256 + kk * 32 + l4 * 8);
#pragma unroll
            for (int n = 0; n < 4; ++n)
                b[n] = *reinterpret_cast<const s16x8*>(Bb + (size_t)n * 16 * 256 + kk * 32);
#pragma unroll
            for (int m = 0; m < 4; ++m)
#pragma unroll
                for (int n = 0; n < 4; ++n)
                    acc[m][n] = __builtin_amdgcn_mfma_f32_16x16x32_bf16(a[m], b[n], acc[m][n], 0, 0, 0);
        }
    }
    __syncthreads();   // everyone done reading Sb half

    // ---- write aggr (+deg*b2) bf16 back into sA[256..511] ----
    {
        float b2v[4];
#pragma unroll
        for (int n = 0; n < 4; ++n) b2v[n] = b2[colBase + n * 16];
#pragma unroll
        for (int m = 0; m < 4; ++m)
#pragma unroll
            for (int j = 0; j < 4; ++j) {
                const int row = m * 16 + l4 * 4 + j;
                const float dv = (float)(base[n0 + row + 1] - base[n0 + row]);
#pragma unroll
                for (int n = 0; n < 4; ++n)
                    sA[row * K2S + 256 + colBase + n * 16] = f2b(acc[m][n][j] + dv * b2v[n]);
            }
    }
    __syncthreads();

    // ---- GEMM1b: (64 x 512) @ U1T^T ----
#pragma unroll
    for (int m = 0; m < 4; ++m)
#pragma unroll
        for (int n = 0; n < 4; ++n) acc[m][n] = z4;
    {
        const u16* Bb = U1T + (size_t)colBase * K2 + l4 * 8;
        for (int kk = 0; kk < 16; ++kk) {
            s16x8 a[4], b[4];
#pragma unroll
            for (int m = 0; m < 4; ++m)
                a[m] = *reinterpret_cast<const s16x8*>(sA + (m * 16 + l15) * K2S + kk * 32 + l4 * 8);
#pragma unroll
            for (int n = 0; n < 4; ++n)
                b[n] = *reinterpret_cast<const s16x8*>(Bb + (size_t)n * 16 * K2 + kk * 32);
#pragma unroll
            for (int m = 0; m < 4; ++m)
#pragma unroll
                for (int n = 0; n < 4; ++n)
                    acc[m][n] = __builtin_amdgcn_mfma_f32_16x16x32_bf16(a[m], b[n], acc[m][n], 0, 0, 0);
        }
    }
    __syncthreads();

    // ---- epilogue 1: +c1, silu, bf16 -> sX ----
    {
        u16* sX = reinterpret_cast<u16*>(smemraw);
        float c1v[4];
#pragma unroll
        for (int n = 0; n < 4; ++n) c1v[n] = c1[colBase + n * 16];
#pragma unroll
        for (int m = 0; m < 4; ++m)
#pragma unroll
            for (int n = 0; n < 4; ++n)
#pragma unroll
                for (int j = 0; j < 4; ++j) {
                    float x = acc[m][n][j] + c1v[n];
                    float s = x * fsig(x);
                    sX[(m * 16 + l4 * 4 + j) * XS + colBase + n * 16] = f2b(s);
                }
    }
    __syncthreads();

    // ---- GEMM2b: (64 x 256) @ U2T^T ----
#pragma unroll
    for (int m = 0; m < 4; ++m)
#pragma unroll
        for (int n = 0; n < 4; ++n) acc[m][n] = z4;
    {
        const u16* sX = reinterpret_cast<u16*>(smemraw);
        const u16* Bb = U2T + (size_t)colBase * H_DIM + l4 * 8;
        for (int kk = 0; kk < 8; ++kk) {
            s16x8 a[4], b[4];
#pragma unroll
            for (int m = 0; m < 4; ++m)
                a[m] = *reinterpret_cast<const s16x8*>(sX + (m * 16 + l15) * XS + kk * 32 + l4 * 8);
#pragma unroll
            for (int n = 0; n < 4; ++n)
                b[n] = *reinterpret_cast<const s16x8*>(Bb + (size_t)n * 16 * H_DIM + kk * 32);
#pragma unroll
            for (int m = 0; m < 4; ++m)
#pragma unroll
                for (int n = 0; n < 4; ++n)
                    acc[m][n] = __builtin_amdgcn_mfma_f32_16x16x32_bf16(a[m], b[n], acc[m][n], 0, 0, 0);
        }
    }
    __syncthreads();   // done reading sX before overwriting as fp32

    // ---- epilogue 2: +c2 + residual -> sF (fp32) ----
    {
        float* sF = reinterpret_cast<float*>(smemraw);   // [64][XS]
        float c2v[4];
#pragma unroll
        for (int n = 0; n < 4; ++n) c2v[n] = c2[colBase + n * 16];
#pragma unroll
        for (int m = 0; m < 4; ++m)
#pragma unroll
            for (int n = 0; n < 4; ++n)
#pragma unroll
                for (int j = 0; j < 4; ++j) {
                    const int row = m * 16 + l4 * 4 + j;
                    const float hv = h[(size_t)(n0 + row) * H_DIM + colBase + n * 16];
                    sF[row * XS + colBase + n * 16] = acc[m][n][j] + c2v[n] + hv;
                }
    }
    __syncthreads();

    // ---- LayerNorm + mask + store (4 threads per row) ----
    {
        const float* sF = reinterpret_cast<const float*>(smemraw);
        const int rr = t >> 2, p = t & 3;
        const float* rowf = sF + rr * XS + p * 64;
        float s1 = 0.f, s2 = 0.f;
#pragma unroll
        for (int i = 0; i < 64; ++i) { float v = rowf[i]; s1 += v; s2 += v * v; }
        s1 += __shfl_xor(s1, 1); s1 += __shfl_xor(s1, 2);
        s2 += __shfl_xor(s2, 1); s2 += __shfl_xor(s2, 2);
        const float mu   = s1 * (1.f / 256.f);
        const float var  = s2 * (1.f / 256.f) - mu * mu;
        const float rstd = rsqrtf(var + 1e-5f);
        const int node = n0 + rr;
        const float mk = mask[node];
        float* op = out + (size_t)node * H_DIM + p * 64;
        const float* gp = gamma + p * 64;
        const float* bp = beta + p * 64;
#pragma unroll
        for (int i = 0; i < 64; i += 4) {
            float4 x  = *reinterpret_cast<const float4*>(rowf + i);
            float4 g4 = *reinterpret_cast<const float4*>(gp + i);
            float4 b4 = *reinterpret_cast<const float4*>(bp + i);
            float4 o;
            o.x = (((x.x - mu) * rstd) * g4.x + b4.x) * mk;
            o.y = (((x.y - mu) * rstd) * g4.y + b4.y) * mk;
            o.z = (((x.z - mu) * rstd) * g4.z + b4.z) * mk;
            o.w = (((x.w - mu) * rstd) * g4.w + b4.w) * mk;
            *reinterpret_cast<float4*>(op + i) = o;
        }
    }
}

// ---------------- workspace layout (bytes) ----------------
// eperm ALIASES the first 2 MB of the PQ region: k_permute (reads eperm) completes
// before k_gemm_pq (writes PQ) on the same stream, so the overlap is safe.
#define OFF_PQ     0ull                      // 32768*512*2  = 33554432
#define OFF_EPERM  0ull                      // 524288*4     = 2097152 (aliases PQ)
#define OFF_SB     33554432ull               // 32768*256*2  = 16777216
#define OFF_EAS    50331648ull               // 524288*16*4  = 33554432
#define OFF_WPQT   83886080ull               // 512*256*2    = 262144
#define OFF_W2T    84148224ull               // 256*256*2    = 131072
#define OFF_U1T    84279296ull               // 256*512*2    = 262144
#define OFF_U2T    84541440ull               // 256*256*2    = 131072
#define OFF_CNT    84672512ull               // 32768*4      = 131072
#define OFF_BASE   84803584ull               // (32768+1)*4 -> 131328
#define OFF_NEXT   84934912ull               // 32768*4      = 131072
#define OFF_ELIST  85065984ull               // 524288*4     = 2097152

extern "C" void kernel_launch(void* const* d_in, const int* in_sizes, int n_in,
                              void* d_out, int out_size, void* d_ws, size_t ws_size,
                              hipStream_t stream) {
    const float* h     = (const float*)d_in[0];
    const int*   eidx  = (const int*)d_in[1];
    const float* ea    = (const float*)d_in[2];
    const float* mask  = (const float*)d_in[3];
    const float* W1    = (const float*)d_in[4];
    const float* b1    = (const float*)d_in[5];
    const float* W2    = (const float*)d_in[6];
    const float* b2    = (const float*)d_in[7];
    const float* U1    = (const float*)d_in[8];
    const float* c1    = (const float*)d_in[9];
    const float* U2    = (const float*)d_in[10];
    const float* c2    = (const float*)d_in[11];
    const float* gamma = (const float*)d_in[12];
    const float* beta  = (const float*)d_in[13];
    float* out = (float*)d_out;
    char*  ws  = (char*)d_ws;

    u16*   PQ    = (u16*)(ws + OFF_PQ);
    int*   eperm = (int*)(ws + OFF_EPERM);   // aliases PQ region (dead before k_gemm_pq)
    u16*   Sb    = (u16*)(ws + OFF_SB);
    float* eas   = (float*)(ws + OFF_EAS);
    u16*   WpqT  = (u16*)(ws + OFF_WPQT);
    u16*   W2T   = (u16*)(ws + OFF_W2T);
    u16*   U1T   = (u16*)(ws + OFF_U1T);
    u16*   U2T   = (u16*)(ws + OFF_U2T);
    int*   cnt   = (int*)(ws + OFF_CNT);
    int*   base  = (int*)(ws + OFF_BASE);
    int*   nxt   = (int*)(ws + OFF_NEXT);
    int*   elist = (int*)(ws + OFF_ELIST);

    hipMemsetAsync(cnt, 0, (size_t)NN * sizeof(int), stream);

    k_prep_w<<<1536, 256, 0, stream>>>(W1, W2, U1, U2, WpqT, W2T, U1T, U2T);
    k_hist<<<E_NUM / 256, 256, 0, stream>>>(eidx, cnt);
    k_scan<<<1, 256, 0, stream>>>(cnt, base, nxt);
    k_scatter<<<E_NUM / 256, 256, 0, stream>>>(eidx, nxt, elist, eperm);
    k_permute<<<E_NUM / 256, 256, 0, stream>>>(eperm, ea, eas);
    k_gemm_pq<<<(NN / 64) * 2, 256, 0, stream>>>(h, WpqT, PQ);
    k_aggr<<<NN / 4, 256, 0, stream>>>(PQ, elist, base, eas, W1, b1, Sb);
    k_post<<<NN / 64, 256, 0, stream>>>(h, Sb, W2T, base, b2, U1T, U2T,
                                        c1, c2, gamma, beta, mask, out);
}

// Round 13
// 281.726 us; speedup vs baseline: 1.0909x; 1.0909x over previous
//
#include <hip/hip_runtime.h>

// ---------------- problem constants ----------------
#define H_DIM 256
#define E_NUM 524288
#define NN    32768          // B*N nodes
#define K2    512            // 2H
#define K2S   520            // LDS row stride (u16) k_post A-tile
#define SAS   264            // LDS row stride (u16) for 256-wide A tiles
#define XS    264            // fp32 intermediate row stride in k_post

typedef unsigned short u16;
typedef unsigned int   u32;
typedef __attribute__((ext_vector_type(8))) short s16x8;
typedef __attribute__((ext_vector_type(4))) float f32x4;
typedef __attribute__((ext_vector_type(2))) float f32x2;
typedef __attribute__((ext_vector_type(4))) unsigned short u16x4;

__device__ __forceinline__ u16 f2b(float x) {
    u32 u = __float_as_uint(x);
    u32 r = (u + 0x7FFFu + ((u >> 16) & 1u)) >> 16;   // RNE; inputs finite
    return (u16)r;
}
__device__ __forceinline__ float b2f(u16 v) {
    u32 u = ((u32)v) << 16;
    return __uint_as_float(u);
}
__device__ __forceinline__ float fsig(float x) {       // fast sigmoid
    return __builtin_amdgcn_rcpf(1.f + __expf(-x));
}

// ---------------- weight prep: build bf16 transposed weights ----------------
__global__ __launch_bounds__(256) void k_prep_w(
    const float* __restrict__ W1, const float* __restrict__ W2,
    const float* __restrict__ U1, const float* __restrict__ U2,
    u16* __restrict__ WpqT, u16* __restrict__ W2T,
    u16* __restrict__ U1T, u16* __restrict__ U2T) {
    int idx = blockIdx.x * 256 + threadIdx.x;
    if (idx < 131072) {                       // WpqT
        int c = idx >> 8, k = idx & 255;
        float v = (c < 256) ? W1[k * 256 + c] : W1[(256 + k) * 256 + (c - 256)];
        WpqT[idx] = f2b(v);
    } else if (idx < 196608) {                // W2T
        int i = idx - 131072; int c = i >> 8, k = i & 255;
        W2T[i] = f2b(W2[k * 256 + c]);
    } else if (idx < 327680) {                // U1T
        int i = idx - 196608; int c = i >> 9, k = i & 511;
        U1T[i] = f2b(U1[(size_t)k * 256 + c]);
    } else if (idx < 393216) {                // U2T
        int i = idx - 327680; int c = i >> 8, k = i & 255;
        U2T[i] = f2b(U2[k * 256 + c]);
    }
}

// ---------------- CSR build ----------------
__global__ __launch_bounds__(256) void k_hist(const int* __restrict__ eidx,
                                              int* __restrict__ cnt) {
    int i = blockIdx.x * 256 + threadIdx.x;
    if (i < E_NUM) atomicAdd(&cnt[eidx[E_NUM + i]], 1);
}

// parallel scan: per-thread 128-chunk sums, wave shfl-scan, LDS cross-wave combine
__global__ __launch_bounds__(256) void k_scan(const int* __restrict__ cnt,
                                              int* __restrict__ base,
                                              int* __restrict__ nxt) {
    __shared__ int wsum[4];
    const int t = threadIdx.x, lane = t & 63, w = t >> 6;
    const int st = t * 128;
    int s = 0;
#pragma unroll 8
    for (int i = 0; i < 128; ++i) s += cnt[st + i];
    int sc = s;                               // inclusive scan within wave
#pragma unroll
    for (int off = 1; off < 64; off <<= 1) {
        int v = __shfl_up(sc, off);
        if (lane >= off) sc += v;
    }
    if (lane == 63) wsum[w] = sc;
    __syncthreads();
    int woff = 0;
    for (int i = 0; i < w; ++i) woff += wsum[i];
    const int excl = woff + sc - s;           // exclusive prefix of this thread's chunk
    if (t == 255) base[NN] = woff + sc;
    int off = excl;
    for (int i = 0; i < 128; ++i) {
        int v = cnt[st + i];
        base[st + i] = off;
        nxt[st + i] = off;
        off += v;
    }
}

// scatter: CSR edge list (src only) + ea rows permuted into CSR order (fused, R9-proven)
__global__ __launch_bounds__(256) void k_scatter(const int* __restrict__ eidx,
                                                 int* __restrict__ nxt,
                                                 int* __restrict__ elist,
                                                 float* __restrict__ eas,
                                                 const float* __restrict__ ea) {
    int i = blockIdx.x * 256 + threadIdx.x;
    if (i < E_NUM) {
        int d = eidx[E_NUM + i];
        int p = atomicAdd(&nxt[d], 1);
        elist[p] = eidx[i];
        const float4* s = reinterpret_cast<const float4*>(ea + (size_t)i * 16);
        float4* o = reinterpret_cast<float4*>(eas + (size_t)p * 16);
        float4 v0 = s[0], v1 = s[1], v2 = s[2], v3 = s[3];
        o[0] = v0; o[1] = v1; o[2] = v2; o[3] = v3;
    }
}

// ---------------- node GEMM: [P|Q] = h @ [W1a|W1b]  (bf16 out, NN x 512) ----------------
// grid = NN/64 blocks; each block stages its h tile ONCE and computes both 256-col halves.
__global__ __launch_bounds__(256, 2) void k_gemm_pq(
    const float* __restrict__ h, const u16* __restrict__ WpqT,
    u16* __restrict__ PQ) {
    __shared__ __align__(16) u16 sA[64 * SAS];
    const int t = threadIdx.x;
    const int n0 = blockIdx.x * 64;
    {   // stage h tile (fp32 -> bf16)
        const int r = t >> 2, g = t & 3;
        const float* hrow = h + (size_t)(n0 + r) * 256;
        u16* rowp = sA + r * SAS;
#pragma unroll
        for (int j = 0; j < 8; ++j) {
            const int c = g + 4 * j;
            float4 v0 = *reinterpret_cast<const float4*>(hrow + c * 8);
            float4 v1 = *reinterpret_cast<const float4*>(hrow + c * 8 + 4);
            s16x8 o;
            o[0] = (short)f2b(v0.x); o[1] = (short)f2b(v0.y);
            o[2] = (short)f2b(v0.z); o[3] = (short)f2b(v0.w);
            o[4] = (short)f2b(v1.x); o[5] = (short)f2b(v1.y);
            o[6] = (short)f2b(v1.z); o[7] = (short)f2b(v1.w);
            *reinterpret_cast<s16x8*>(rowp + c * 8) = o;
        }
    }
    __syncthreads();
    const int lane = t & 63, wv = t >> 6;
    const int l15 = lane & 15, l4 = lane >> 4;
    const int colBase = wv * 64 + l15;
    const f32x4 z4 = {0.f, 0.f, 0.f, 0.f};

    for (int q = 0; q < 2; ++q) {
        f32x4 acc[4][4];
#pragma unroll
        for (int m = 0; m < 4; ++m)
#pragma unroll
            for (int n = 0; n < 4; ++n) acc[m][n] = z4;
        const u16* Bb = WpqT + (size_t)(q * 256 + colBase) * 256 + l4 * 8;
        for (int kk = 0; kk < 8; ++kk) {
            s16x8 a[4], b[4];
#pragma unroll
            for (int m = 0; m < 4; ++m)
                a[m] = *reinterpret_cast<const s16x8*>(sA + (m * 16 + l15) * SAS + kk * 32 + l4 * 8);
#pragma unroll
            for (int n = 0; n < 4; ++n)
                b[n] = *reinterpret_cast<const s16x8*>(Bb + (size_t)n * 16 * 256 + kk * 32);
#pragma unroll
            for (int m = 0; m < 4; ++m)
#pragma unroll
                for (int n = 0; n < 4; ++n)
                    acc[m][n] = __builtin_amdgcn_mfma_f32_16x16x32_bf16(a[m], b[n], acc[m][n], 0, 0, 0);
        }
#pragma unroll
        for (int m = 0; m < 4; ++m)
#pragma unroll
            for (int j = 0; j < 4; ++j) {
                const int row = n0 + m * 16 + l4 * 4 + j;
                u16* op = PQ + (size_t)row * 512 + q * 256 + colBase;
#pragma unroll
                for (int n = 0; n < 4; ++n) op[n * 16] = f2b(acc[m][n][j]);
            }
    }
}

// ---------------- aggregation: S[d] = sum_e silu(P[src]+Q[d]+R[e]), bf16 out ----------------
// grid = NN/4 blocks x 4 waves; ONE dst node per wave (4x wave oversubscription for TLP).
// depth-4 pipelined PQ gathers; ea pre-sorted to CSR order -> sequential uniform loads.
// (R9 configuration: proven best at ~103 us; pins/attrs regressed in R10/R11.)

// load CSR-ordered ea row (uniform, sequential) for window edge k (clamped to m-1)
#define LDEA(S0, S1, S2, S3, k) do {                                        \
    const float* _ep = eas + (size_t)(eBeg + cb + min((k), m - 1)) * 16;    \
    S0 = *reinterpret_cast<const float4*>(_ep);                             \
    S1 = *reinterpret_cast<const float4*>(_ep + 4);                         \
    S2 = *reinterpret_cast<const float4*>(_ep + 8);                         \
    S3 = *reinterpret_cast<const float4*>(_ep + 12);                        \
} while (0)

__global__ __launch_bounds__(256, 4) void k_aggr(
    const u16* __restrict__ PQ, const int* __restrict__ elist,
    const int* __restrict__ base, const float* __restrict__ eas,
    const float* __restrict__ W1, const float* __restrict__ b1,
    u16* __restrict__ Sb) {
    const int t = threadIdx.x, lane = t & 63, wv = t >> 6;
    const int c0 = lane * 4;
    // W1c (rows 512..527) in registers as f32x2 pairs (v_pk_fma_f32)
    f32x2 WrL[16], WrH[16];
#pragma unroll
    for (int k = 0; k < 16; ++k) {
        float4 w = *reinterpret_cast<const float4*>(W1 + (size_t)(512 + k) * 256 + c0);
        WrL[k] = f32x2{w.x, w.y};
        WrH[k] = f32x2{w.z, w.w};
    }
    const float4 b1v = *reinterpret_cast<const float4*>(b1 + c0);

    const int d = __builtin_amdgcn_readfirstlane(blockIdx.x * 4 + wv);
    f32x2 qbL = {b1v.x, b1v.y}, qbH = {b1v.z, b1v.w};
    {
        u16x4 qv = *reinterpret_cast<const u16x4*>(PQ + (size_t)d * 512 + 256 + c0);
        qbL[0] += b2f(qv.x); qbL[1] += b2f(qv.y);
        qbH[0] += b2f(qv.z); qbH[1] += b2f(qv.w);
    }
    const int eBeg = __builtin_amdgcn_readfirstlane(base[d]);
    const int nAll = __builtin_amdgcn_readfirstlane(base[d + 1]) - eBeg;
    f32x2 accL = {0.f, 0.f}, accH = {0.f, 0.f};

    for (int cb = 0; cb < nAll; cb += 64) {
        const int m = min(64, nAll - cb);
        // lane-own src staging (lanes >= m duplicate edge m-1) -> any readlane idx<64 safe
        const int eeX = elist[eBeg + cb + min(lane, m - 1)];

        auto gather = [&](int idx) -> u16x4 {
            const int s = __builtin_amdgcn_readlane(eeX, idx);   // SGPR base
            return *reinterpret_cast<const u16x4*>(PQ + (size_t)s * 512 + c0);
        };
        auto edge_compute = [&](const u16x4& pc, const float4& E0, const float4& E1,
                                const float4& E2, const float4& E3) {
            f32x2 xL = qbL, xH = qbH;
            xL[0] += b2f(pc.x); xL[1] += b2f(pc.y);
            xH[0] += b2f(pc.z); xH[1] += b2f(pc.w);
            xL = xL + WrL[0]  * E0.x; xH = xH + WrH[0]  * E0.x;
            xL = xL + WrL[1]  * E0.y; xH = xH + WrH[1]  * E0.y;
            xL = xL + WrL[2]  * E0.z; xH = xH + WrH[2]  * E0.z;
            xL = xL + WrL[3]  * E0.w; xH = xH + WrH[3]  * E0.w;
            xL = xL + WrL[4]  * E1.x; xH = xH + WrH[4]  * E1.x;
            xL = xL + WrL[5]  * E1.y; xH = xH + WrH[5]  * E1.y;
            xL = xL + WrL[6]  * E1.z; xH = xH + WrH[6]  * E1.z;
            xL = xL + WrL[7]  * E1.w; xH = xH + WrH[7]  * E1.w;
            xL = xL + WrL[8]  * E2.x; xH = xH + WrH[8]  * E2.x;
            xL = xL + WrL[9]  * E2.y; xH = xH + WrH[9]  * E2.y;
            xL = xL + WrL[10] * E2.z; xH = xH + WrH[10] * E2.z;
            xL = xL + WrL[11] * E2.w; xH = xH + WrH[11] * E2.w;
            xL = xL + WrL[12] * E3.x; xH = xH + WrH[12] * E3.x;
            xL = xL + WrL[13] * E3.y; xH = xH + WrH[13] * E3.y;
            xL = xL + WrL[14] * E3.z; xH = xH + WrH[14] * E3.z;
            xL = xL + WrL[15] * E3.w; xH = xH + WrH[15] * E3.w;
            accL[0] += xL[0] * fsig(xL[0]);
            accL[1] += xL[1] * fsig(xL[1]);
            accH[0] += xH[0] * fsig(xH[0]);
            accH[1] += xH[1] * fsig(xH[1]);
        };

        // pipeline: depth-4 p-gathers, depth-2 ea buffers (A/B), all named regs
        u16x4 p0 = gather(0), p1 = gather(1), p2 = gather(2), p3 = gather(3);
        float4 A0, A1, A2, A3, B0, B1, B2, B3;
        LDEA(A0, A1, A2, A3, 0);
        LDEA(B0, B1, B2, B3, 1);
        int kb = 0;
        for (; kb + 4 <= m; kb += 4) {
            edge_compute(p0, A0, A1, A2, A3);
            LDEA(A0, A1, A2, A3, kb + 2);
            p0 = gather(min(kb + 4, 63));
            edge_compute(p1, B0, B1, B2, B3);
            LDEA(B0, B1, B2, B3, kb + 3);
            p1 = gather(min(kb + 5, 63));
            edge_compute(p2, A0, A1, A2, A3);
            LDEA(A0, A1, A2, A3, kb + 4);
            p2 = gather(min(kb + 6, 63));
            edge_compute(p3, B0, B1, B2, B3);
            LDEA(B0, B1, B2, B3, kb + 5);
            p3 = gather(min(kb + 7, 63));
        }
        // tail (<=3 edges); after loop A holds ea[kb], B holds ea[kb+1] (clamped)
        if (kb + 0 < m) edge_compute(p0, A0, A1, A2, A3);
        if (kb + 1 < m) edge_compute(p1, B0, B1, B2, B3);
        if (kb + 2 < m) {
            LDEA(A0, A1, A2, A3, kb + 2);
            edge_compute(p2, A0, A1, A2, A3);
        }
    }
    u16x4 o;
    o.x = f2b(accL[0]); o.y = f2b(accL[1]);
    o.z = f2b(accH[0]); o.w = f2b(accH[1]);
    *reinterpret_cast<u16x4*>(Sb + (size_t)d * 256 + c0) = o;
}

// ---------------- fused: aggr GEMM (Sb@W2 + deg*b2) + update MLP + residual + LN + mask ----------------
__global__ __launch_bounds__(256, 2) void k_post(
    const float* __restrict__ h, const u16* __restrict__ Sb,
    const u16* __restrict__ W2T, const int* __restrict__ base,
    const float* __restrict__ b2,
    const u16* __restrict__ U1T, const u16* __restrict__ U2T,
    const float* __restrict__ c1, const float* __restrict__ c2,
    const float* __restrict__ gamma, const float* __restrict__ beta,
    const float* __restrict__ mask,
    float* __restrict__ out) {
    __shared__ __align__(16) char smemraw[64 * XS * 4];  // 67584 B, multi-purpose
    u16* sA = reinterpret_cast<u16*>(smemraw);           // [64][K2S] bf16
    const int t  = threadIdx.x;
    const int n0 = blockIdx.x * 64;

    {   // stage [h(bf16) | Sb] -> sA
        const int r = t >> 2, g = t & 3;
        const int node = n0 + r;
        const float* hrow = h + (size_t)node * H_DIM;
        const u16* srow = Sb + (size_t)node * H_DIM;
        u16* rowp = sA + r * K2S;
#pragma unroll
        for (int j = 0; j < 16; ++j) {
            const int c = g + 4 * j;   // 0..63
            if (c < 32) {
                float4 v0 = *reinterpret_cast<const float4*>(hrow + c * 8);
                float4 v1 = *reinterpret_cast<const float4*>(hrow + c * 8 + 4);
                s16x8 o;
                o[0] = (short)f2b(v0.x); o[1] = (short)f2b(v0.y);
                o[2] = (short)f2b(v0.z); o[3] = (short)f2b(v0.w);
                o[4] = (short)f2b(v1.x); o[5] = (short)f2b(v1.y);
                o[6] = (short)f2b(v1.z); o[7] = (short)f2b(v1.w);
                *reinterpret_cast<s16x8*>(rowp + c * 8) = o;
            } else {
                const int cc = c - 32;
                *reinterpret_cast<s16x8*>(rowp + 256 + cc * 8) =
                    *reinterpret_cast<const s16x8*>(srow + cc * 8);
            }
        }
    }
    __syncthreads();

    const int lane = t & 63, wv = t >> 6;
    const int l15 = lane & 15, l4 = lane >> 4;
    const int colBase = wv * 64 + l15;
    const f32x4 z4 = {0.f, 0.f, 0.f, 0.f};

    f32x4 acc[4][4];
#pragma unroll
    for (int m = 0; m < 4; ++m)
#pragma unroll
        for (int n = 0; n < 4; ++n) acc[m][n] = z4;

    // ---- GEMM-S: aggr = Sb @ W2 (A from sA[256..511], K=256) ----
    {
        const u16* Bb = W2T + (size_t)colBase * 256 + l4 * 8;
        for (int kk = 0; kk < 8; ++kk) {
            s16x8 a[4], b[4];
#pragma unroll
            for (int m = 0; m < 4; ++m)
                a[m] = *reinterpret_cast<const s16x8*>(sA + (m * 16 + l15) * K2S + 256 + kk * 32 + l4 * 8);
#pragma unroll
            for (int n = 0; n < 4; ++n)
                b[n] = *reinterpret_cast<const s16x8*>(Bb + (size_t)n * 16 * 256 + kk * 32);
#pragma unroll
            for (int m = 0; m < 4; ++m)
#pragma unroll
                for (int n = 0; n < 4; ++n)
                    acc[m][n] = __builtin_amdgcn_mfma_f32_16x16x32_bf16(a[m], b[n], acc[m][n], 0, 0, 0);
        }
    }
    __syncthreads();   // everyone done reading Sb half

    // ---- write aggr (+deg*b2) bf16 back into sA[256..511] ----
    {
        float b2v[4];
#pragma unroll
        for (int n = 0; n < 4; ++n) b2v[n] = b2[colBase + n * 16];
#pragma unroll
        for (int m = 0; m < 4; ++m)
#pragma unroll
            for (int j = 0; j < 4; ++j) {
                const int row = m * 16 + l4 * 4 + j;
                const float dv = (float)(base[n0 + row + 1] - base[n0 + row]);
#pragma unroll
                for (int n = 0; n < 4; ++n)
                    sA[row * K2S + 256 + colBase + n * 16] = f2b(acc[m][n][j] + dv * b2v[n]);
            }
    }
    __syncthreads();

    // ---- GEMM1b: (64 x 512) @ U1T^T ----
#pragma unroll
    for (int m = 0; m < 4; ++m)
#pragma unroll
        for (int n = 0; n < 4; ++n) acc[m][n] = z4;
    {
        const u16* Bb = U1T + (size_t)colBase * K2 + l4 * 8;
        for (int kk = 0; kk < 16; ++kk) {
            s16x8 a[4], b[4];
#pragma unroll
            for (int m = 0; m < 4; ++m)
                a[m] = *reinterpret_cast<const s16x8*>(sA + (m * 16 + l15) * K2S + kk * 32 + l4 * 8);
#pragma unroll
            for (int n = 0; n < 4; ++n)
                b[n] = *reinterpret_cast<const s16x8*>(Bb + (size_t)n * 16 * K2 + kk * 32);
#pragma unroll
            for (int m = 0; m < 4; ++m)
#pragma unroll
                for (int n = 0; n < 4; ++n)
                    acc[m][n] = __builtin_amdgcn_mfma_f32_16x16x32_bf16(a[m], b[n], acc[m][n], 0, 0, 0);
        }
    }
    __syncthreads();

    // ---- epilogue 1: +c1, silu, bf16 -> sX ----
    {
        u16* sX = reinterpret_cast<u16*>(smemraw);
        float c1v[4];
#pragma unroll
        for (int n = 0; n < 4; ++n) c1v[n] = c1[colBase + n * 16];
#pragma unroll
        for (int m = 0; m < 4; ++m)
#pragma unroll
            for (int n = 0; n < 4; ++n)
#pragma unroll
                for (int j = 0; j < 4; ++j) {
                    float x = acc[m][n][j] + c1v[n];
                    float s = x * fsig(x);
                    sX[(m * 16 + l4 * 4 + j) * XS + colBase + n * 16] = f2b(s);
                }
    }
    __syncthreads();

    // ---- GEMM2b: (64 x 256) @ U2T^T ----
#pragma unroll
    for (int m = 0; m < 4; ++m)
#pragma unroll
        for (int n = 0; n < 4; ++n) acc[m][n] = z4;
    {
        const u16* sX = reinterpret_cast<u16*>(smemraw);
        const u16* Bb = U2T + (size_t)colBase * H_DIM + l4 * 8;
        for (int kk = 0; kk < 8; ++kk) {
            s16x8 a[4], b[4];
#pragma unroll
            for (int m = 0; m < 4; ++m)
                a[m] = *reinterpret_cast<const s16x8*>(sX + (m * 16 + l15) * XS + kk * 32 + l4 * 8);
#pragma unroll
            for (int n = 0; n < 4; ++n)
                b[n] = *reinterpret_cast<const s16x8*>(Bb + (size_t)n * 16 * H_DIM + kk * 32);
#pragma unroll
            for (int m = 0; m < 4; ++m)
#pragma unroll
                for (int n = 0; n < 4; ++n)
                    acc[m][n] = __builtin_amdgcn_mfma_f32_16x16x32_bf16(a[m], b[n], acc[m][n], 0, 0, 0);
        }
    }
    __syncthreads();   // done reading sX before overwriting as fp32

    // ---- epilogue 2: +c2 + residual -> sF (fp32) ----
    {
        float* sF = reinterpret_cast<float*>(smemraw);   // [64][XS]
        float c2v[4];
#pragma unroll
        for (int n = 0; n < 4; ++n) c2v[n] = c2[colBase + n * 16];
#pragma unroll
        for (int m = 0; m < 4; ++m)
#pragma unroll
            for (int n = 0; n < 4; ++n)
#pragma unroll
                for (int j = 0; j < 4; ++j) {
                    const int row = m * 16 + l4 * 4 + j;
                    const float hv = h[(size_t)(n0 + row) * H_DIM + colBase + n * 16];
                    sF[row * XS + colBase + n * 16] = acc[m][n][j] + c2v[n] + hv;
                }
    }
    __syncthreads();

    // ---- LayerNorm + mask + store (4 threads per row) ----
    {
        const float* sF = reinterpret_cast<const float*>(smemraw);
        const int rr = t >> 2, p = t & 3;
        const float* rowf = sF + rr * XS + p * 64;
        float s1 = 0.f, s2 = 0.f;
#pragma unroll
        for (int i = 0; i < 64; ++i) { float v = rowf[i]; s1 += v; s2 += v * v; }
        s1 += __shfl_xor(s1, 1); s1 += __shfl_xor(s1, 2);
        s2 += __shfl_xor(s2, 1); s2 += __shfl_xor(s2, 2);
        const float mu   = s1 * (1.f / 256.f);
        const float var  = s2 * (1.f / 256.f) - mu * mu;
        const float rstd = rsqrtf(var + 1e-5f);
        const int node = n0 + rr;
        const float mk = mask[node];
        float* op = out + (size_t)node * H_DIM + p * 64;
        const float* gp = gamma + p * 64;
        const float* bp = beta + p * 64;
#pragma unroll
        for (int i = 0; i < 64; i += 4) {
            float4 x  = *reinterpret_cast<const float4*>(rowf + i);
            float4 g4 = *reinterpret_cast<const float4*>(gp + i);
            float4 b4 = *reinterpret_cast<const float4*>(bp + i);
            float4 o;
            o.x = (((x.x - mu) * rstd) * g4.x + b4.x) * mk;
            o.y = (((x.y - mu) * rstd) * g4.y + b4.y) * mk;
            o.z = (((x.z - mu) * rstd) * g4.z + b4.z) * mk;
            o.w = (((x.w - mu) * rstd) * g4.w + b4.w) * mk;
            *reinterpret_cast<float4*>(op + i) = o;
        }
    }
}

// ---------------- workspace layout (bytes) ----------------
#define OFF_PQ     0ull                      // 32768*512*2  = 33554432
#define OFF_SB     33554432ull               // 32768*256*2  = 16777216
#define OFF_EAS    50331648ull               // 524288*16*4  = 33554432
#define OFF_WPQT   83886080ull               // 512*256*2    = 262144
#define OFF_W2T    84148224ull               // 256*256*2    = 131072
#define OFF_U1T    84279296ull               // 256*512*2    = 262144
#define OFF_U2T    84541440ull               // 256*256*2    = 131072
#define OFF_CNT    84672512ull               // 32768*4      = 131072
#define OFF_BASE   84803584ull               // (32768+1)*4 -> 131328
#define OFF_NEXT   84934912ull               // 32768*4      = 131072
#define OFF_ELIST  85065984ull               // 524288*4     = 2097152

extern "C" void kernel_launch(void* const* d_in, const int* in_sizes, int n_in,
                              void* d_out, int out_size, void* d_ws, size_t ws_size,
                              hipStream_t stream) {
    const float* h     = (const float*)d_in[0];
    const int*   eidx  = (const int*)d_in[1];
    const float* ea    = (const float*)d_in[2];
    const float* mask  = (const float*)d_in[3];
    const float* W1    = (const float*)d_in[4];
    const float* b1    = (const float*)d_in[5];
    const float* W2    = (const float*)d_in[6];
    const float* b2    = (const float*)d_in[7];
    const float* U1    = (const float*)d_in[8];
    const float* c1    = (const float*)d_in[9];
    const float* U2    = (const float*)d_in[10];
    const float* c2    = (const float*)d_in[11];
    const float* gamma = (const float*)d_in[12];
    const float* beta  = (const float*)d_in[13];
    float* out = (float*)d_out;
    char*  ws  = (char*)d_ws;

    u16*   PQ    = (u16*)(ws + OFF_PQ);
    u16*   Sb    = (u16*)(ws + OFF_SB);
    float* eas   = (float*)(ws + OFF_EAS);
    u16*   WpqT  = (u16*)(ws + OFF_WPQT);
    u16*   W2T   = (u16*)(ws + OFF_W2T);
    u16*   U1T   = (u16*)(ws + OFF_U1T);
    u16*   U2T   = (u16*)(ws + OFF_U2T);
    int*   cnt   = (int*)(ws + OFF_CNT);
    int*   base  = (int*)(ws + OFF_BASE);
    int*   nxt   = (int*)(ws + OFF_NEXT);
    int*   elist = (int*)(ws + OFF_ELIST);

    hipMemsetAsync(cnt, 0, (size_t)NN * sizeof(int), stream);

    k_prep_w<<<1536, 256, 0, stream>>>(W1, W2, U1, U2, WpqT, W2T, U1T, U2T);
    k_hist<<<E_NUM / 256, 256, 0, stream>>>(eidx, cnt);
    k_scan<<<1, 256, 0, stream>>>(cnt, base, nxt);
    k_scatter<<<E_NUM / 256, 256, 0, stream>>>(eidx, nxt, elist, eas, ea);
    k_gemm_pq<<<NN / 64, 256, 0, stream>>>(h, WpqT, PQ);
    k_aggr<<<NN / 4, 256, 0, stream>>>(PQ, elist, base, eas, W1, b1, Sb);
    k_post<<<NN / 64, 256, 0, stream>>>(h, Sb, W2T, base, b2, U1T, U2T,
                                        c1, c2, gamma, beta, mask, out);
}